// Round 8
// baseline (118.210 us; speedup 1.0000x reference)
//
#include <hip/hip_runtime.h>

#define B_ 32
#define C_ 64
#define N_ 1024
#define T_ 64

typedef __attribute__((ext_vector_type(8))) _Float16 half8;   // 8 f16 = 4 VGPR
typedef __attribute__((ext_vector_type(4))) _Float16 half4;
typedef __attribute__((ext_vector_type(4))) float f32x4;

// ---------------------------------------------------------------------------
// K1 (R22): q-reduction (unchanged NT stream) + FUSED qw prologue.
// R21 analysis: K2 = 17.2us drain (at write ceiling) + ~12us serial prologue.
// K1 is read-BW-bound with MFMA/VALU/LDS idle -> the split-precision qw MFMA
// moves here for free. qw f16 stash lives in the first 128 B of each out row
// (row r stash written by r's K1 owner, read by r's unique K2 owner BEFORE
// that same block overwrites the row -> no cross-block hazard, no extra ws).
// MFMA inputs bit-identical to R21 (same q_f16, same f32 W hi/lo split).
// ---------------------------------------------------------------------------
__global__ __launch_bounds__(256) void k_q(const float* __restrict__ x,
                                           const float* __restrict__ W,
                                           const float* __restrict__ alpha,
                                           _Float16* __restrict__ q_h,
                                           float* __restrict__ out) {
    const int bid = blockIdx.x;
    const int s1  = (bid & 7) * 256 + (bid >> 3);   // bijective, 2048%8==0
    const int b   = s1 >> 6;
    const int n0  = (s1 & 63) * 16;
    const int tid = threadIdx.x;

    __shared__ float Ws[T_][T_];                    // 16 KB fp32 W
    __shared__ _Float16 qsh[16][72];                // 2.25 KB f16 q tile

    // ---- stage W (fp32, coalesced; L2/L3-hot, 4 loads/thread) ----
    {
        const f32x4* Wv = (const f32x4*)W;
        f32x4* Wd = (f32x4*)&Ws[0][0];
        Wd[tid]       = Wv[tid];
        Wd[tid + 256] = Wv[tid + 256];
        Wd[tid + 512] = Wv[tid + 512];
        Wd[tid + 768] = Wv[tid + 768];
    }

    // ---- q = sum_c alpha[c] * x  (NT read-once stream, unchanged) ----
    const f32x4* xb = (const f32x4*)(x + (size_t)b * C_ * N_ * T_
                                       + (size_t)n0 * T_);
    f32x4 acc = {0.f, 0.f, 0.f, 0.f};
#pragma unroll 4
    for (int c = 0; c < C_; ++c) {
        f32x4 v = __builtin_nontemporal_load(&xb[(size_t)c * (N_ * T_ / 4) + tid]);
        const float ac = alpha[c];
        acc[0] += ac * v[0]; acc[1] += ac * v[1];
        acc[2] += ac * v[2]; acc[3] += ac * v[3];
    }

    half4 h;
#pragma unroll
    for (int j = 0; j < 4; ++j) h[j] = (_Float16)acc[j];   // RTNE cvt
    *(half4*)(q_h + ((size_t)b * N_ + n0) * T_ + (size_t)tid * 4) = h;

    // ---- q tile -> LDS (row = tid>>4, cols (tid&15)*4..+3) ----
    *(half4*)&qsh[tid >> 4][(tid & 15) * 4] = h;
    __syncthreads();

    // ---- qw = q @ W via MFMA, split-precision W; wave w -> col block w ----
    {
        const int w    = tid >> 6;                  // 0..3
        const int lane = tid & 63;
        const int lr   = lane & 15;
        const int lk   = lane >> 4;

        half8 a0 = *(const half8*)&qsh[lr][lk * 8];        // A row lr, k lk*8..
        half8 a1 = *(const half8*)&qsh[lr][lk * 8 + 32];
        half8 bh0, bh1, bl0, bl1;
#pragma unroll
        for (int j = 0; j < 8; ++j) {
            const float wv0 = Ws[lk * 8 + j][w * 16 + lr];
            const float wv1 = Ws[lk * 8 + 32 + j][w * 16 + lr];
            const _Float16 h0 = (_Float16)wv0;
            const _Float16 h1 = (_Float16)wv1;
            bh0[j] = h0; bl0[j] = (_Float16)(wv0 - (float)h0);
            bh1[j] = h1; bl1[j] = (_Float16)(wv1 - (float)h1);
        }
        f32x4 a = {0.f, 0.f, 0.f, 0.f};
        a = __builtin_amdgcn_mfma_f32_16x16x32_f16(a0, bh0, a, 0, 0, 0);
        a = __builtin_amdgcn_mfma_f32_16x16x32_f16(a1, bh1, a, 0, 0, 0);
        a = __builtin_amdgcn_mfma_f32_16x16x32_f16(a0, bl0, a, 0, 0, 0);
        a = __builtin_amdgcn_mfma_f32_16x16x32_f16(a1, bl1, a, 0, 0, 0);

        // C layout: col = lr, row = lk*4 + r. Stash qw[row][col] as f16 in
        // the first 128 B of global out row (n0+row).
        char* sb = (char*)out
                 + ((size_t)(b * N_ + n0 + lk * 4) * N_) * 4 + (w * 16 + lr) * 2;
#pragma unroll
        for (int r = 0; r < 4; ++r)
            *(_Float16*)(sb + (size_t)r * N_ * 4) = (_Float16)a[r];
    }
}

// ---------------------------------------------------------------------------
// K2 (R22): R21's store-streaming 4-tile body; prologue collapsed to
// {stash->LDS (1 half8/thread) + 16 bst loads + ONE barrier}. All global
// loads complete before the first store (R19 vmcnt-FIFO lesson). Tile loop:
// zero global loads, LDS-only barriers (lgkmcnt(0)+s_barrier), red[2] dbuf,
// tile g's stores drain under tile g+1's compute. 512 blocks x 512 thr.
// ---------------------------------------------------------------------------
__global__ __launch_bounds__(512, 4) void k_scores_softmax(
        const _Float16* __restrict__ q_h,
        float* __restrict__ out) {
    const int bid = blockIdx.x;
    const int s   = (bid & 7) * 64 + (bid >> 3);    // bijective, 512%8==0
    const int b   = s >> 4;                         // same b<->XCD map as K1
    const int n0  = (s & 15) * 64;                  // 64-row tile base
    const int tid  = threadIdx.x;
    const int w    = tid >> 6;                      // wave 0..7 -> cols w*128
    const int lane = tid & 63;
    const int lr   = lane & 15;
    const int lk   = lane >> 4;

    __shared__ _Float16 qwh[64][72];                // 9 KB f16 qw tile (64 rows)
    __shared__ float red[2][16][8];                 // 1 KB, double-buffered

    // ---- stash -> qwh LDS (coalesced: 8 lanes x 16 B per out row) ----
    {
        const int r  = tid >> 3;                    // 0..63
        const int c8 = (tid & 7) * 8;               // f16 col
        half8 hv = *(const half8*)((const char*)out
                     + ((size_t)(b * N_ + n0 + r) * N_) * 4 + (size_t)c8 * 2);
        *(half8*)&qwh[r][c8] = hv;
    }

    // ---- load ALL 16 B-stripe frags ONCE (tile-independent) ----
    half8 bst0[8], bst1[8];                         // 64 VGPR, live whole loop
    {
        const size_t cb0 = ((size_t)b * N_ + w * 128 + lr) * T_ + lk * 8;
#pragma unroll
        for (int cf = 0; cf < 8; ++cf) {
            bst0[cf] = *(const half8*)(q_h + cb0 + (size_t)cf * 16 * T_);
            bst1[cf] = *(const half8*)(q_h + cb0 + (size_t)cf * 16 * T_ + 32);
        }
    }
    __syncthreads();                                // all loads done; qwh ready

    float* const obase = out + ((size_t)b * N_ + n0 + lr) * N_ + w * 128 + lk * 4;

    // ---- 4 row-tiles; tile g's stores drain under tile g+1's compute ----
#pragma unroll 1
    for (int g = 0; g < 4; ++g) {
        half8 af0 = *(const half8*)&qwh[g * 16 + lr][lk * 8];
        half8 af1 = *(const half8*)&qwh[g * 16 + lr][lk * 8 + 32];

        f32x4 acc[8];
#pragma unroll
        for (int cf = 0; cf < 8; ++cf) {
            // swapped operands: lane owns out row n0+g*16+lr,
            // reg r = col w*128+cf*16+lk*4+r (4 consecutive floats)
            f32x4 a = {0.f, 0.f, 0.f, 0.f};
            a = __builtin_amdgcn_mfma_f32_16x16x32_f16(bst0[cf], af0, a, 0, 0, 0);
            a = __builtin_amdgcn_mfma_f32_16x16x32_f16(bst1[cf], af1, a, 0, 0, 0);
            acc[cf] = a;
        }

        // ---- max-free softmax for these 16 rows ----
        float ssum = 0.f;
#pragma unroll
        for (int cf = 0; cf < 8; ++cf) {
#pragma unroll
            for (int r = 0; r < 4; ++r) {
                float e = __expf(acc[cf][r]);
                acc[cf][r] = e;
                ssum += e;
            }
        }
        ssum += __shfl_xor(ssum, 16);               // sum across lk group
        ssum += __shfl_xor(ssum, 32);
        if (lane < 16) red[g & 1][lr][w] = ssum;

        // LDS-ONLY barrier: lgkmcnt drained, vmcnt NOT -> prior tile's global
        // stores keep draining under this barrier and the next tile's compute.
        asm volatile("s_waitcnt lgkmcnt(0)" ::: "memory");
        __builtin_amdgcn_s_barrier();
        asm volatile("" ::: "memory");

        f32x4 p0 = *(f32x4*)&red[g & 1][lr][0];
        f32x4 p1 = *(f32x4*)&red[g & 1][lr][4];
        const float inv = 1.0f / (p0[0] + p0[1] + p0[2] + p0[3] +
                                  p1[0] + p1[1] + p1[2] + p1[3]);
        f32x4* orow = (f32x4*)(obase + (size_t)g * 16 * N_);
#pragma unroll
        for (int cf = 0; cf < 8; ++cf) {
            f32x4 v = acc[cf];
            v[0] *= inv; v[1] *= inv; v[2] *= inv; v[3] *= inv;
            orow[cf * 4] = v;                       // dwordx4; no vmcnt consumer
        }
    }
}

// ---------------------------------------------------------------------------
extern "C" void kernel_launch(void* const* d_in, const int* in_sizes, int n_in,
                              void* d_out, int out_size, void* d_ws, size_t ws_size,
                              hipStream_t stream) {
    const float* x     = (const float*)d_in[0];
    const float* W     = (const float*)d_in[1];
    const float* alpha = (const float*)d_in[2];
    float* out = (float*)d_out;

    _Float16* q_h = (_Float16*)d_ws;                // [B,N,T] f16, 4 MB

    k_q<<<2048, 256, 0, stream>>>(x, W, alpha, q_h, out);
    k_scores_softmax<<<512, 512, 0, stream>>>(q_h, out);
}